// Round 19
// baseline (323.895 us; speedup 1.0000x reference)
//
#include <hip/hip_runtime.h>
#include <cstdint>

typedef unsigned short u16;
typedef __bf16 bf16x8 __attribute__((ext_vector_type(8)));
typedef float f32x4 __attribute__((ext_vector_type(4)));
typedef unsigned short u16x8 __attribute__((ext_vector_type(8)));
typedef unsigned short u16x4 __attribute__((ext_vector_type(4)));

// ---------- helpers ----------
__device__ __forceinline__ u16 f2b(float f) {  // fp32 -> bf16 RNE
  union { float f; unsigned u; } x; x.f = f;
  unsigned r = (x.u + 0x7FFFu + ((x.u >> 16) & 1u)) >> 16;
  return (u16)r;
}
__device__ __forceinline__ float b2f(u16 v) {
  union { unsigned u; float f; } x; x.u = (unsigned)v << 16; return x.f;
}

__device__ __forceinline__ void gload_lds16(const void* g, void* l) {
  __builtin_amdgcn_global_load_lds(
      (__attribute__((address_space(1))) void*)(uintptr_t)g,
      (__attribute__((address_space(3))) void*)(uintptr_t)l, 16, 0, 0);
}

// ---------- fused fp32 -> bf16 cast over 5 regions (8 floats/thread) ----------
struct CastArgs {
  const float* in[5];
  u16* out[5];
  int cum[6];   // cumulative float8 counts
};
__global__ void cast_multi(CastArgs a) {
  const int i = blockIdx.x * 256 + threadIdx.x;
  int r = 0;
#pragma unroll
  for (int k = 1; k < 5; ++k) r += (i >= a.cum[k]);
  const int local = i - a.cum[r];
  const float4 v0 = *(const float4*)(a.in[r] + (size_t)local * 8);
  const float4 v1 = *(const float4*)(a.in[r] + (size_t)local * 8 + 4);
  u16x8 o = {f2b(v0.x), f2b(v0.y), f2b(v0.z), f2b(v0.w),
             f2b(v1.x), f2b(v1.y), f2b(v1.z), f2b(v1.w)};
  *(u16x8*)(a.out[r] + (size_t)local * 8) = o;
}

// ---------- GEMM 128x128 (2-barrier), T2 chunk-swizzled LDS ----------
// WRITE_VT: for QKV gemm, cols >= 2048 (V part) go transposed into Vt.
template<bool GELU_ACT, bool WRITE_VT>
__global__ void gemm_nt(const u16* __restrict__ A, const u16* __restrict__ Bw,
                        const float* __restrict__ bias, u16* __restrict__ Cb,
                        u16* __restrict__ Vt, int M, int N, int K) {
  __shared__ u16 As[2][128 * 32];
  __shared__ u16 Bs[2][128 * 32];
  const int tid = threadIdx.x;
  const int lane = tid & 63, wid = tid >> 6;
  const int bm = blockIdx.y * 128, bn = blockIdx.x * 128;
  const int wm = wid >> 1, wn = wid & 1;
  const int r = lane & 15, g = lane >> 4;
  const int s4 = (r >> 1) & 3;           // per-lane read swizzle

  auto stage = [&](int buf, int k0) {
#pragma unroll
    for (int i = 0; i < 2; ++i) {
      const int c = tid + i * 256;
      const int row = c >> 2, ch = c & 3;
      const int gs = ch ^ ((row >> 1) & 3);
      gload_lds16(A + (size_t)(bm + row) * K + k0 + gs * 8, &As[buf][c * 8]);
      gload_lds16(Bw + (size_t)(bn + row) * K + k0 + gs * 8, &Bs[buf][c * 8]);
    }
  };

  f32x4 acc[4][4] = {};
  stage(0, 0);
  __syncthreads();
  const int nk = K >> 5;
  int cur = 0;
  for (int kt = 0; kt < nk; ++kt) {
    if (kt + 1 < nk) stage(cur ^ 1, (kt + 1) * 32);
    bf16x8 af[4], bfr[4];
#pragma unroll
    for (int m = 0; m < 4; ++m)
      af[m] = *(const bf16x8*)&As[cur][(wm * 64 + m * 16 + r) * 32 + (g ^ s4) * 8];
#pragma unroll
    for (int n = 0; n < 4; ++n)
      bfr[n] = *(const bf16x8*)&Bs[cur][(wn * 64 + n * 16 + r) * 32 + (g ^ s4) * 8];
#pragma unroll
    for (int m = 0; m < 4; ++m)
#pragma unroll
      for (int n = 0; n < 4; ++n)
        acc[m][n] = __builtin_amdgcn_mfma_f32_16x16x32_bf16(af[m], bfr[n], acc[m][n], 0, 0, 0);
    __syncthreads();
    cur ^= 1;
  }
#pragma unroll
  for (int m = 0; m < 4; ++m) {
    const int row0 = bm + wm * 64 + m * 16 + g * 4;
#pragma unroll
    for (int n = 0; n < 4; ++n) {
      const int col = bn + wn * 64 + n * 16 + r;
      const float bv = bias[col];
      if (WRITE_VT && col >= 2048) {
        // V part: write transposed. batch = row0>>10, s0 = row0&1023.
        const int hv = col - 2048;
        const int bb = row0 >> 10, s0 = row0 & 1023;
        u16x4 ov;
#pragma unroll
        for (int j = 0; j < 4; ++j) ov[j] = f2b(acc[m][n][j] + bv);
        *(u16x4*)(Vt + (((size_t)(bb * 16 + (hv >> 6))) * 64 + (hv & 63)) * 1024 + s0) = ov;
      } else {
#pragma unroll
        for (int j = 0; j < 4; ++j) {
          float v = acc[m][n][j] + bv;
          if (GELU_ACT) v = 0.5f * v * (1.f + erff(v * 0.70710678118654752f));
          Cb[(size_t)(row0 + j) * N + col] = f2b(v);
        }
      }
    }
  }
}

// ---------- GEMM 128x128 split-K (chunk-swizzled): bf16 partials ----------
__global__ void gemm_nt_splitk(const u16* __restrict__ A, const u16* __restrict__ Bw,
                               u16* __restrict__ parts, int M, int N, int K, int Kc) {
  __shared__ u16 As[2][128 * 32];
  __shared__ u16 Bs[2][128 * 32];
  const int tid = threadIdx.x;
  const int lane = tid & 63, wid = tid >> 6;
  const int bm = blockIdx.y * 128, bn = blockIdx.x * 128;
  const int kbase = blockIdx.z * Kc;
  const int wm = wid >> 1, wn = wid & 1;
  const int r = lane & 15, g = lane >> 4;
  const int s4 = (r >> 1) & 3;

  auto stage = [&](int buf, int k0) {
#pragma unroll
    for (int i = 0; i < 2; ++i) {
      const int c = tid + i * 256;
      const int row = c >> 2, ch = c & 3;
      const int gs = ch ^ ((row >> 1) & 3);
      gload_lds16(A + (size_t)(bm + row) * K + k0 + gs * 8, &As[buf][c * 8]);
      gload_lds16(Bw + (size_t)(bn + row) * K + k0 + gs * 8, &Bs[buf][c * 8]);
    }
  };

  f32x4 acc[4][4] = {};
  stage(0, kbase);
  __syncthreads();
  const int nk = Kc >> 5;
  int cur = 0;
  for (int kt = 0; kt < nk; ++kt) {
    if (kt + 1 < nk) stage(cur ^ 1, kbase + (kt + 1) * 32);
    bf16x8 af[4], bfr[4];
#pragma unroll
    for (int m = 0; m < 4; ++m)
      af[m] = *(const bf16x8*)&As[cur][(wm * 64 + m * 16 + r) * 32 + (g ^ s4) * 8];
#pragma unroll
    for (int n = 0; n < 4; ++n)
      bfr[n] = *(const bf16x8*)&Bs[cur][(wn * 64 + n * 16 + r) * 32 + (g ^ s4) * 8];
#pragma unroll
    for (int m = 0; m < 4; ++m)
#pragma unroll
      for (int n = 0; n < 4; ++n)
        acc[m][n] = __builtin_amdgcn_mfma_f32_16x16x32_bf16(af[m], bfr[n], acc[m][n], 0, 0, 0);
    __syncthreads();
    cur ^= 1;
  }
  u16* Cp = parts + (size_t)blockIdx.z * M * N;
#pragma unroll
  for (int m = 0; m < 4; ++m) {
    const int row0 = bm + wm * 64 + m * 16 + g * 4;
#pragma unroll
    for (int n = 0; n < 4; ++n) {
      const int col = bn + wn * 64 + n * 16 + r;
#pragma unroll
      for (int j = 0; j < 4; ++j)
        Cp[(size_t)(row0 + j) * N + col] = f2b(acc[m][n][j]);
    }
  }
}

// ---------- fused attention v17: QBLK=64, 4 q-tiles/block, shared K/V loads ----
// Each K-fragment load feeds 8 MFMA (4 tiles x 2); each V load feeds 4 chains.
// LDS 128 KB (4 P-tiles), 1 block/CU. XCD-local bias grouping preserved.
__global__ __launch_bounds__(256) void attn_kernel(
    const u16* __restrict__ qkv, const u16* __restrict__ Vt,
    const float* __restrict__ bias, u16* __restrict__ ctx) {
  const int fid = blockIdx.x;             // 0..1023
  const int xcd = fid & 7, slot = fid >> 3;   // slot 0..127
  const int G = xcd * 32 + (slot >> 2);   // 0..255 = h*16 + qgroup
  const int b = slot & 3;
  const int h = G >> 4;
  const int q0 = (G & 15) * 64;           // 4 consecutive 16-row tiles
  const int tid = threadIdx.x;
  const int lane = tid & 63, wid = tid >> 6;
  const int r = lane & 15, g = lane >> 4;
  const int bh = b * 16 + h;

  __shared__ __align__(16) u16 PB[4][16 * 1024];   // 128 KB

  // Q fragments for 4 tiles
  bf16x8 aq0[4], aq1[4];
#pragma unroll
  for (int t = 0; t < 4; ++t) {
    const size_t qb = (size_t)(b * 1024 + q0 + t * 16 + r) * 3072 + h * 64;
    aq0[t] = *(const bf16x8*)(qkv + qb + g * 8);
    aq1[t] = *(const bf16x8*)(qkv + qb + 32 + g * 8);
  }

  const int n0 = wid * 256;

  // pass A: shared K loads (2-deep prefetch); 8 MFMA per K-fragment pair
  const u16* kptr = qkv + (size_t)(b * 1024 + n0 + r) * 3072 + 1024 + h * 64;
  const size_t kstep = (size_t)16 * 3072;
  bf16x8 k0a = *(const bf16x8*)(kptr + g * 8);
  bf16x8 k1a = *(const bf16x8*)(kptr + 32 + g * 8);
#pragma unroll
  for (int nt = 0; nt < 16; ++nt) {
    bf16x8 k0b, k1b;
    if (nt + 1 < 16) {
      const u16* kn = kptr + (size_t)(nt + 1) * kstep;
      k0b = *(const bf16x8*)(kn + g * 8);
      k1b = *(const bf16x8*)(kn + 32 + g * 8);
    }
    f32x4 a[4];
#pragma unroll
    for (int t = 0; t < 4; ++t) {
      a[t] = f32x4{0.f, 0.f, 0.f, 0.f};
      a[t] = __builtin_amdgcn_mfma_f32_16x16x32_bf16(k0a, aq0[t], a[t], 0, 0, 0);
      a[t] = __builtin_amdgcn_mfma_f32_16x16x32_bf16(k1a, aq1[t], a[t], 0, 0, 0);
    }
    const int col = n0 + nt * 16 + g * 4;
    const int idx = r * 1024 + (col ^ ((r & 15) << 3));
#pragma unroll
    for (int t = 0; t < 4; ++t) {
      u16x4 o = {f2b(a[t][0] * 0.125f), f2b(a[t][1] * 0.125f),
                 f2b(a[t][2] * 0.125f), f2b(a[t][3] * 0.125f)};
      *(u16x4*)&PB[t][idx] = o;
    }
    k0a = k0b;
    k1a = k1b;
  }
  __syncthreads();

  // pass B: wave wid owns tile t = wid (16 complete rows)
#pragma unroll
  for (int lr = 0; lr < 16; ++lr) {
    const int swz = lr << 3;
    u16* prow = &PB[wid][lr * 1024];
    const float* brow = bias + ((size_t)h * 1024 + q0 + wid * 16 + lr) * 1024;
    const int c0 = lane * 16;
    float bb[16];
    *(float4*)&bb[0]  = *(const float4*)(brow + c0);
    *(float4*)&bb[4]  = *(const float4*)(brow + c0 + 4);
    *(float4*)&bb[8]  = *(const float4*)(brow + c0 + 8);
    *(float4*)&bb[12] = *(const float4*)(brow + c0 + 12);
    const u16x8 v0 = *(const u16x8*)&prow[c0 ^ swz];
    const u16x8 v1 = *(const u16x8*)&prow[(c0 + 8) ^ swz];
    float f[16];
#pragma unroll
    for (int k = 0; k < 8; ++k) {
      f[k]     = b2f(v0[k]) + bb[k];
      f[8 + k] = b2f(v1[k]) + bb[8 + k];
    }
    float m = f[0];
#pragma unroll
    for (int k = 1; k < 16; ++k) m = fmaxf(m, f[k]);
    m = fmaxf(m, __shfl_xor(m, 1));  m = fmaxf(m, __shfl_xor(m, 2));
    m = fmaxf(m, __shfl_xor(m, 4));  m = fmaxf(m, __shfl_xor(m, 8));
    m = fmaxf(m, __shfl_xor(m, 16)); m = fmaxf(m, __shfl_xor(m, 32));
    float s = 0.f;
#pragma unroll
    for (int k = 0; k < 16; ++k) { f[k] = __expf(f[k] - m); s += f[k]; }
    s += __shfl_xor(s, 1);  s += __shfl_xor(s, 2);
    s += __shfl_xor(s, 4);  s += __shfl_xor(s, 8);
    s += __shfl_xor(s, 16); s += __shfl_xor(s, 32);
    const float inv = 1.f / s;
    u16x8 o0, o1;
#pragma unroll
    for (int k = 0; k < 8; ++k) {
      o0[k] = f2b(f[k] * inv);
      o1[k] = f2b(f[8 + k] * inv);
    }
    *(u16x8*)&prow[c0 ^ swz] = o0;
    *(u16x8*)&prow[(c0 + 8) ^ swz] = o1;
  }
  __syncthreads();

  // pass C (PV): wave wid owns d-tile wid; one V load feeds 4 tile-chains
  f32x4 oacc[4] = {};
  const u16* vrow = Vt + ((size_t)bh * 64 + wid * 16 + r) * 1024;
  bf16x8 vba = *(const bf16x8*)(vrow + g * 8);
#pragma unroll
  for (int ks = 0; ks < 32; ++ks) {
    bf16x8 vbb;
    if (ks + 1 < 32) vbb = *(const bf16x8*)(vrow + (ks + 1) * 32 + g * 8);
    const int off = (ks * 32 + g * 8) ^ ((r & 15) << 3);
#pragma unroll
    for (int t = 0; t < 4; ++t) {
      const bf16x8 pa = *(const bf16x8*)&PB[t][r * 1024 + off];
      oacc[t] = __builtin_amdgcn_mfma_f32_16x16x32_bf16(pa, vba, oacc[t], 0, 0, 0);
    }
    vba = vbb;
  }
#pragma unroll
  for (int t = 0; t < 4; ++t)
#pragma unroll
    for (int j = 0; j < 4; ++j)
      ctx[(size_t)(b * 1024 + q0 + t * 16 + g * 4 + j) * 1024 + h * 64 + wid * 16 + r] =
          f2b(oacc[t][j]);
}

// ---------- LayerNorm over D=1024 with NP bf16 split-K partials + resid + colbias --
template<int NP, bool RESID_BF16>
__global__ void ln_sum_kernel(const u16* __restrict__ parts,
                              const void* __restrict__ resid,
                              const float* __restrict__ cbias,
                              const float* __restrict__ gw, const float* __restrict__ bw,
                              float* __restrict__ outf, u16* __restrict__ outb) {
  const int row = blockIdx.x, tid = threadIdx.x;
  const size_t off = (size_t)row * 1024 + tid * 4;
  float4 v;
  if (RESID_BF16) {
    const u16x4 rb = *(const u16x4*)((const u16*)resid + off);
    v.x = b2f(rb[0]); v.y = b2f(rb[1]); v.z = b2f(rb[2]); v.w = b2f(rb[3]);
  } else {
    v = *(const float4*)((const float*)resid + off);
  }
  const float4 cb = *(const float4*)(cbias + tid * 4);
  v.x += cb.x; v.y += cb.y; v.z += cb.z; v.w += cb.w;
#pragma unroll
  for (int p = 0; p < NP; ++p) {
    const u16x4 a = *(const u16x4*)(parts + (size_t)p * 4096 * 1024 + off);
    v.x += b2f(a[0]); v.y += b2f(a[1]); v.z += b2f(a[2]); v.w += b2f(a[3]);
  }
  float s = v.x + v.y + v.z + v.w;
  float q = v.x * v.x + v.y * v.y + v.z * v.z + v.w * v.w;
#pragma unroll
  for (int m = 32; m >= 1; m >>= 1) { s += __shfl_xor(s, m); q += __shfl_xor(q, m); }
  __shared__ float rs[4], rq[4];
  if ((tid & 63) == 0) { rs[tid >> 6] = s; rq[tid >> 6] = q; }
  __syncthreads();
  s = rs[0] + rs[1] + rs[2] + rs[3];
  q = rq[0] + rq[1] + rq[2] + rq[3];
  const float mu = s * (1.f / 1024.f);
  const float inv = rsqrtf(q * (1.f / 1024.f) - mu * mu + 1e-5f);
  const float4 g4 = *(const float4*)(gw + tid * 4);
  const float4 b4 = *(const float4*)(bw + tid * 4);
  float4 o;
  o.x = (v.x - mu) * inv * g4.x + b4.x;
  o.y = (v.y - mu) * inv * g4.y + b4.y;
  o.z = (v.z - mu) * inv * g4.z + b4.z;
  o.w = (v.w - mu) * inv * g4.w + b4.w;
  if (outf) *(float4*)(outf + off) = o;
  if (outb) {
    u16x4 ob = {f2b(o.x), f2b(o.y), f2b(o.z), f2b(o.w)};
    *(u16x4*)(outb + off) = ob;
  }
}

// ---------- launch ----------
extern "C" void kernel_launch(void* const* d_in, const int* in_sizes, int n_in,
                              void* d_out, int out_size, void* d_ws, size_t ws_size,
                              hipStream_t stream) {
  (void)in_sizes; (void)n_in; (void)out_size; (void)ws_size;
  const float* src   = (const float*)d_in[0];
  const float* abias = (const float*)d_in[1];
  const float* Wqkv  = (const float*)d_in[2];
  const float* bqkv  = (const float*)d_in[3];
  const float* Wo    = (const float*)d_in[4];
  const float* bo    = (const float*)d_in[5];
  const float* g1    = (const float*)d_in[6];
  const float* b1n   = (const float*)d_in[7];
  const float* g2    = (const float*)d_in[8];
  const float* b2n   = (const float*)d_in[9];
  const float* W1    = (const float*)d_in[10];
  const float* b1    = (const float*)d_in[11];
  const float* W2    = (const float*)d_in[12];
  const float* b2    = (const float*)d_in[13];
  float* out = (float*)d_out;

  char* ws = (char*)d_ws;
  const size_t MB = 1024 * 1024;
  // lifetime-aliased layout, <=104 MB
  u16* srcb  = (u16*)(ws + 0 * MB);      // dead after QKV gemm
  u16* ctxb  = (u16*)(ws + 0 * MB);      // alias (attn out, dead after Wo)
  u16* xb    = (u16*)(ws + 0 * MB);      // alias (ln1 out; resid for final LN)
  u16* Wqkvb = (u16*)(ws + 8 * MB);      // dead after QKV gemm
  u16* Wob   = (u16*)(ws + 14 * MB);     // dead after Wo gemm
  u16* W2b   = (u16*)(ws + 24 * MB);     // live until FF2
  u16* qkvb  = (u16*)(ws + 32 * MB);     // Q,K (V goes to Vt); dead after attn
  u16* Vt    = (u16*)(ws + 56 * MB);     // 8 MB; dead after attn
  u16* hb    = (u16*)(ws + 32 * MB);     // alias (FF1 out, 32 MB)
  u16* parts = (u16*)(ws + 64 * MB);     // 16 MB: bf16 split-K partials
  u16* W1b   = (u16*)(ws + 96 * MB);     // 8 MB; dead after FF1

  // one fused cast launch (src, Wqkv, Wo, W1, W2), 8 floats/thread
  CastArgs ca;
  ca.in[0] = src;  ca.out[0] = srcb;
  ca.in[1] = Wqkv; ca.out[1] = Wqkvb;
  ca.in[2] = Wo;   ca.out[2] = Wob;
  ca.in[3] = W1;   ca.out[3] = W1b;
  ca.in[4] = W2;   ca.out[4] = W2b;
  ca.cum[0] = 0;
  ca.cum[1] = 524288;
  ca.cum[2] = 524288 + 393216;
  ca.cum[3] = 524288 + 393216 + 131072;
  ca.cum[4] = 524288 + 393216 + 131072 + 524288;
  ca.cum[5] = 2097152;
  cast_multi<<<2097152 / 256, 256, 0, stream>>>(ca);

  // qkv = src @ Wqkv^T + bqkv -> Q,K into qkvb; V written transposed to Vt
  gemm_nt<false, true><<<dim3(3072 / 128, 4096 / 128), 256, 0, stream>>>(
      srcb, Wqkvb, bqkv, qkvb, Vt, 4096, 3072, 1024);
  // attention -> ctx bf16 [4096, 1024]  (QBLK=64, 1024 blocks)
  attn_kernel<<<1024, 256, 0, stream>>>(qkvb, Vt, abias, ctxb);
  // Wo split-K x2 (bf16 partials)
  gemm_nt_splitk<<<dim3(1024 / 128, 4096 / 128, 2), 256, 0, stream>>>(
      ctxb, Wob, parts, 4096, 1024, 1024, 512);
  // x = LN(part0+part1+bo+src) -> bf16 only
  ln_sum_kernel<2, false><<<4096, 256, 0, stream>>>(
      parts, src, bo, g1, b1n, nullptr, xb);
  // h = gelu(x @ W1^T + b1) -> bf16 [4096, 4096]
  gemm_nt<true, false><<<dim3(4096 / 128, 4096 / 128), 256, 0, stream>>>(
      xb, W1b, b1, hb, nullptr, 4096, 4096, 1024);
  // FF2 split-K x2 (bf16 partials)
  gemm_nt_splitk<<<dim3(1024 / 128, 4096 / 128, 2), 256, 0, stream>>>(
      hb, W2b, parts, 4096, 1024, 4096, 2048);
  // out = LN(part0+part1+b2+x)   (x as bf16 residual)
  ln_sum_kernel<2, true><<<4096, 256, 0, stream>>>(
      parts, xb, b2, g2, b2n, out, nullptr);
}

// Round 20
// 287.476 us; speedup vs baseline: 1.1267x; 1.1267x over previous
//
#include <hip/hip_runtime.h>
#include <cstdint>

typedef unsigned short u16;
typedef __bf16 bf16x8 __attribute__((ext_vector_type(8)));
typedef float f32x4 __attribute__((ext_vector_type(4)));
typedef unsigned short u16x8 __attribute__((ext_vector_type(8)));
typedef unsigned short u16x4 __attribute__((ext_vector_type(4)));

// ---------- helpers ----------
__device__ __forceinline__ u16 f2b(float f) {  // fp32 -> bf16 RNE
  union { float f; unsigned u; } x; x.f = f;
  unsigned r = (x.u + 0x7FFFu + ((x.u >> 16) & 1u)) >> 16;
  return (u16)r;
}
__device__ __forceinline__ float b2f(u16 v) {
  union { unsigned u; float f; } x; x.u = (unsigned)v << 16; return x.f;
}

__device__ __forceinline__ void gload_lds16(const void* g, void* l) {
  __builtin_amdgcn_global_load_lds(
      (__attribute__((address_space(1))) void*)(uintptr_t)g,
      (__attribute__((address_space(3))) void*)(uintptr_t)l, 16, 0, 0);
}

// ---------- fused fp32 -> bf16 cast over 5 regions (8 floats/thread) ----------
struct CastArgs {
  const float* in[5];
  u16* out[5];
  int cum[6];   // cumulative float8 counts
};
__global__ void cast_multi(CastArgs a) {
  const int i = blockIdx.x * 256 + threadIdx.x;
  int r = 0;
#pragma unroll
  for (int k = 1; k < 5; ++k) r += (i >= a.cum[k]);
  const int local = i - a.cum[r];
  const float4 v0 = *(const float4*)(a.in[r] + (size_t)local * 8);
  const float4 v1 = *(const float4*)(a.in[r] + (size_t)local * 8 + 4);
  u16x8 o = {f2b(v0.x), f2b(v0.y), f2b(v0.z), f2b(v0.w),
             f2b(v1.x), f2b(v1.y), f2b(v1.z), f2b(v1.w)};
  *(u16x8*)(a.out[r] + (size_t)local * 8) = o;
}

// ---------- GEMM 128x128 (2-barrier), T2 chunk-swizzled LDS ----------
// WRITE_VT: for QKV gemm, cols >= 2048 (V part) go transposed into Vt.
template<bool GELU_ACT, bool WRITE_VT>
__global__ void gemm_nt(const u16* __restrict__ A, const u16* __restrict__ Bw,
                        const float* __restrict__ bias, u16* __restrict__ Cb,
                        u16* __restrict__ Vt, int M, int N, int K) {
  __shared__ u16 As[2][128 * 32];
  __shared__ u16 Bs[2][128 * 32];
  const int tid = threadIdx.x;
  const int lane = tid & 63, wid = tid >> 6;
  const int bm = blockIdx.y * 128, bn = blockIdx.x * 128;
  const int wm = wid >> 1, wn = wid & 1;
  const int r = lane & 15, g = lane >> 4;
  const int s4 = (r >> 1) & 3;           // per-lane read swizzle

  auto stage = [&](int buf, int k0) {
#pragma unroll
    for (int i = 0; i < 2; ++i) {
      const int c = tid + i * 256;
      const int row = c >> 2, ch = c & 3;
      const int gs = ch ^ ((row >> 1) & 3);
      gload_lds16(A + (size_t)(bm + row) * K + k0 + gs * 8, &As[buf][c * 8]);
      gload_lds16(Bw + (size_t)(bn + row) * K + k0 + gs * 8, &Bs[buf][c * 8]);
    }
  };

  f32x4 acc[4][4] = {};
  stage(0, 0);
  __syncthreads();
  const int nk = K >> 5;
  int cur = 0;
  for (int kt = 0; kt < nk; ++kt) {
    if (kt + 1 < nk) stage(cur ^ 1, (kt + 1) * 32);
    bf16x8 af[4], bfr[4];
#pragma unroll
    for (int m = 0; m < 4; ++m)
      af[m] = *(const bf16x8*)&As[cur][(wm * 64 + m * 16 + r) * 32 + (g ^ s4) * 8];
#pragma unroll
    for (int n = 0; n < 4; ++n)
      bfr[n] = *(const bf16x8*)&Bs[cur][(wn * 64 + n * 16 + r) * 32 + (g ^ s4) * 8];
#pragma unroll
    for (int m = 0; m < 4; ++m)
#pragma unroll
      for (int n = 0; n < 4; ++n)
        acc[m][n] = __builtin_amdgcn_mfma_f32_16x16x32_bf16(af[m], bfr[n], acc[m][n], 0, 0, 0);
    __syncthreads();
    cur ^= 1;
  }
#pragma unroll
  for (int m = 0; m < 4; ++m) {
    const int row0 = bm + wm * 64 + m * 16 + g * 4;
#pragma unroll
    for (int n = 0; n < 4; ++n) {
      const int col = bn + wn * 64 + n * 16 + r;
      const float bv = bias[col];
      if (WRITE_VT && col >= 2048) {
        // V part: write transposed. batch = row0>>10, s0 = row0&1023.
        const int hv = col - 2048;
        const int bb = row0 >> 10, s0 = row0 & 1023;
        u16x4 ov;
#pragma unroll
        for (int j = 0; j < 4; ++j) ov[j] = f2b(acc[m][n][j] + bv);
        *(u16x4*)(Vt + (((size_t)(bb * 16 + (hv >> 6))) * 64 + (hv & 63)) * 1024 + s0) = ov;
      } else {
#pragma unroll
        for (int j = 0; j < 4; ++j) {
          float v = acc[m][n][j] + bv;
          if (GELU_ACT) v = 0.5f * v * (1.f + erff(v * 0.70710678118654752f));
          Cb[(size_t)(row0 + j) * N + col] = f2b(v);
        }
      }
    }
  }
}

// ---------- GEMM 128x128 split-K (chunk-swizzled): bf16 partials ----------
__global__ void gemm_nt_splitk(const u16* __restrict__ A, const u16* __restrict__ Bw,
                               u16* __restrict__ parts, int M, int N, int K, int Kc) {
  __shared__ u16 As[2][128 * 32];
  __shared__ u16 Bs[2][128 * 32];
  const int tid = threadIdx.x;
  const int lane = tid & 63, wid = tid >> 6;
  const int bm = blockIdx.y * 128, bn = blockIdx.x * 128;
  const int kbase = blockIdx.z * Kc;
  const int wm = wid >> 1, wn = wid & 1;
  const int r = lane & 15, g = lane >> 4;
  const int s4 = (r >> 1) & 3;

  auto stage = [&](int buf, int k0) {
#pragma unroll
    for (int i = 0; i < 2; ++i) {
      const int c = tid + i * 256;
      const int row = c >> 2, ch = c & 3;
      const int gs = ch ^ ((row >> 1) & 3);
      gload_lds16(A + (size_t)(bm + row) * K + k0 + gs * 8, &As[buf][c * 8]);
      gload_lds16(Bw + (size_t)(bn + row) * K + k0 + gs * 8, &Bs[buf][c * 8]);
    }
  };

  f32x4 acc[4][4] = {};
  stage(0, kbase);
  __syncthreads();
  const int nk = Kc >> 5;
  int cur = 0;
  for (int kt = 0; kt < nk; ++kt) {
    if (kt + 1 < nk) stage(cur ^ 1, kbase + (kt + 1) * 32);
    bf16x8 af[4], bfr[4];
#pragma unroll
    for (int m = 0; m < 4; ++m)
      af[m] = *(const bf16x8*)&As[cur][(wm * 64 + m * 16 + r) * 32 + (g ^ s4) * 8];
#pragma unroll
    for (int n = 0; n < 4; ++n)
      bfr[n] = *(const bf16x8*)&Bs[cur][(wn * 64 + n * 16 + r) * 32 + (g ^ s4) * 8];
#pragma unroll
    for (int m = 0; m < 4; ++m)
#pragma unroll
      for (int n = 0; n < 4; ++n)
        acc[m][n] = __builtin_amdgcn_mfma_f32_16x16x32_bf16(af[m], bfr[n], acc[m][n], 0, 0, 0);
    __syncthreads();
    cur ^= 1;
  }
  u16* Cp = parts + (size_t)blockIdx.z * M * N;
#pragma unroll
  for (int m = 0; m < 4; ++m) {
    const int row0 = bm + wm * 64 + m * 16 + g * 4;
#pragma unroll
    for (int n = 0; n < 4; ++n) {
      const int col = bn + wn * 64 + n * 16 + r;
#pragma unroll
      for (int j = 0; j < 4; ++j)
        Cp[(size_t)(row0 + j) * N + col] = f2b(acc[m][n][j]);
    }
  }
}

// ---------- fused attention v16 (r18 best: QBLK=32, 2-deep prefetch, XCD bias) ----
__global__ __launch_bounds__(256) void attn_kernel(
    const u16* __restrict__ qkv, const u16* __restrict__ Vt,
    const float* __restrict__ bias, u16* __restrict__ ctx) {
  const int fid = blockIdx.x;
  const int xcd = fid & 7, slot = fid >> 3;
  const int G = xcd * 64 + (slot >> 2);
  const int b = slot & 3;
  const int h = G >> 5;
  const int q0 = (G & 31) * 32;
  const int tid = threadIdx.x;
  const int lane = tid & 63, wid = tid >> 6;
  const int r = lane & 15, g = lane >> 4;
  const int bh = b * 16 + h;

  __shared__ __align__(16) u16 PB[2][16 * 1024];

  const size_t qb0 = (size_t)(b * 1024 + q0 + r) * 3072 + h * 64;
  const size_t qb1 = (size_t)(b * 1024 + q0 + 16 + r) * 3072 + h * 64;
  const bf16x8 aq00 = *(const bf16x8*)(qkv + qb0 + g * 8);
  const bf16x8 aq01 = *(const bf16x8*)(qkv + qb0 + 32 + g * 8);
  const bf16x8 aq10 = *(const bf16x8*)(qkv + qb1 + g * 8);
  const bf16x8 aq11 = *(const bf16x8*)(qkv + qb1 + 32 + g * 8);

  const int n0 = wid * 256;

  const u16* kptr = qkv + (size_t)(b * 1024 + n0 + r) * 3072 + 1024 + h * 64;
  const size_t kstep = (size_t)16 * 3072;
  bf16x8 k0a = *(const bf16x8*)(kptr + g * 8);
  bf16x8 k1a = *(const bf16x8*)(kptr + 32 + g * 8);
#pragma unroll
  for (int nt = 0; nt < 16; ++nt) {
    bf16x8 k0b, k1b;
    if (nt + 1 < 16) {
      const u16* kn = kptr + (size_t)(nt + 1) * kstep;
      k0b = *(const bf16x8*)(kn + g * 8);
      k1b = *(const bf16x8*)(kn + 32 + g * 8);
    }
    f32x4 a0 = {0.f, 0.f, 0.f, 0.f}, a1 = {0.f, 0.f, 0.f, 0.f};
    a0 = __builtin_amdgcn_mfma_f32_16x16x32_bf16(k0a, aq00, a0, 0, 0, 0);
    a1 = __builtin_amdgcn_mfma_f32_16x16x32_bf16(k0a, aq10, a1, 0, 0, 0);
    a0 = __builtin_amdgcn_mfma_f32_16x16x32_bf16(k1a, aq01, a0, 0, 0, 0);
    a1 = __builtin_amdgcn_mfma_f32_16x16x32_bf16(k1a, aq11, a1, 0, 0, 0);
    const int col = n0 + nt * 16 + g * 4;
    const int idx = r * 1024 + (col ^ ((r & 15) << 3));
    u16x4 o0 = {f2b(a0[0] * 0.125f), f2b(a0[1] * 0.125f),
                f2b(a0[2] * 0.125f), f2b(a0[3] * 0.125f)};
    u16x4 o1 = {f2b(a1[0] * 0.125f), f2b(a1[1] * 0.125f),
                f2b(a1[2] * 0.125f), f2b(a1[3] * 0.125f)};
    *(u16x4*)&PB[0][idx] = o0;
    *(u16x4*)&PB[1][idx] = o1;
    k0a = k0b;
    k1a = k1b;
  }
  __syncthreads();

#pragma unroll
  for (int tr = 0; tr < 8; ++tr) {
    const int t = tr & 1, rr = tr >> 1;
    const int row = wid * 4 + rr;
    const int swz = (row & 15) << 3;
    u16* prow = &PB[t][row * 1024];
    const float* brow = bias + ((size_t)h * 1024 + q0 + t * 16 + row) * 1024;
    const int c0 = lane * 16;
    float bb[16];
    *(float4*)&bb[0]  = *(const float4*)(brow + c0);
    *(float4*)&bb[4]  = *(const float4*)(brow + c0 + 4);
    *(float4*)&bb[8]  = *(const float4*)(brow + c0 + 8);
    *(float4*)&bb[12] = *(const float4*)(brow + c0 + 12);
    const u16x8 v0 = *(const u16x8*)&prow[c0 ^ swz];
    const u16x8 v1 = *(const u16x8*)&prow[(c0 + 8) ^ swz];
    float f[16];
#pragma unroll
    for (int k = 0; k < 8; ++k) {
      f[k]     = b2f(v0[k]) + bb[k];
      f[8 + k] = b2f(v1[k]) + bb[8 + k];
    }
    float m = f[0];
#pragma unroll
    for (int k = 1; k < 16; ++k) m = fmaxf(m, f[k]);
    m = fmaxf(m, __shfl_xor(m, 1));  m = fmaxf(m, __shfl_xor(m, 2));
    m = fmaxf(m, __shfl_xor(m, 4));  m = fmaxf(m, __shfl_xor(m, 8));
    m = fmaxf(m, __shfl_xor(m, 16)); m = fmaxf(m, __shfl_xor(m, 32));
    float s = 0.f;
#pragma unroll
    for (int k = 0; k < 16; ++k) { f[k] = __expf(f[k] - m); s += f[k]; }
    s += __shfl_xor(s, 1);  s += __shfl_xor(s, 2);
    s += __shfl_xor(s, 4);  s += __shfl_xor(s, 8);
    s += __shfl_xor(s, 16); s += __shfl_xor(s, 32);
    const float inv = 1.f / s;
    u16x8 o0, o1;
#pragma unroll
    for (int k = 0; k < 8; ++k) {
      o0[k] = f2b(f[k] * inv);
      o1[k] = f2b(f[8 + k] * inv);
    }
    *(u16x8*)&prow[c0 ^ swz] = o0;
    *(u16x8*)&prow[(c0 + 8) ^ swz] = o1;
  }
  __syncthreads();

  f32x4 oa = {0.f, 0.f, 0.f, 0.f}, ob = {0.f, 0.f, 0.f, 0.f};
  const u16* vrow = Vt + ((size_t)bh * 64 + wid * 16 + r) * 1024;
  bf16x8 vba = *(const bf16x8*)(vrow + g * 8);
#pragma unroll
  for (int ks = 0; ks < 32; ++ks) {
    bf16x8 vbb;
    if (ks + 1 < 32) vbb = *(const bf16x8*)(vrow + (ks + 1) * 32 + g * 8);
    const int off = (ks * 32 + g * 8) ^ ((r & 15) << 3);
    const bf16x8 pa0 = *(const bf16x8*)&PB[0][r * 1024 + off];
    const bf16x8 pa1 = *(const bf16x8*)&PB[1][r * 1024 + off];
    oa = __builtin_amdgcn_mfma_f32_16x16x32_bf16(pa0, vba, oa, 0, 0, 0);
    ob = __builtin_amdgcn_mfma_f32_16x16x32_bf16(pa1, vba, ob, 0, 0, 0);
    vba = vbb;
  }
#pragma unroll
  for (int j = 0; j < 4; ++j) {
    ctx[(size_t)(b * 1024 + q0 + g * 4 + j) * 1024 + h * 64 + wid * 16 + r] = f2b(oa[j]);
    ctx[(size_t)(b * 1024 + q0 + 16 + g * 4 + j) * 1024 + h * 64 + wid * 16 + r] = f2b(ob[j]);
  }
}

// ---------- LayerNorm over D=1024 with NP bf16 split-K partials + resid + colbias --
template<int NP, bool RESID_BF16>
__global__ void ln_sum_kernel(const u16* __restrict__ parts,
                              const void* __restrict__ resid,
                              const float* __restrict__ cbias,
                              const float* __restrict__ gw, const float* __restrict__ bw,
                              float* __restrict__ outf, u16* __restrict__ outb) {
  const int row = blockIdx.x, tid = threadIdx.x;
  const size_t off = (size_t)row * 1024 + tid * 4;
  float4 v;
  if (RESID_BF16) {
    const u16x4 rb = *(const u16x4*)((const u16*)resid + off);
    v.x = b2f(rb[0]); v.y = b2f(rb[1]); v.z = b2f(rb[2]); v.w = b2f(rb[3]);
  } else {
    v = *(const float4*)((const float*)resid + off);
  }
  const float4 cb = *(const float4*)(cbias + tid * 4);
  v.x += cb.x; v.y += cb.y; v.z += cb.z; v.w += cb.w;
#pragma unroll
  for (int p = 0; p < NP; ++p) {
    const u16x4 a = *(const u16x4*)(parts + (size_t)p * 4096 * 1024 + off);
    v.x += b2f(a[0]); v.y += b2f(a[1]); v.z += b2f(a[2]); v.w += b2f(a[3]);
  }
  float s = v.x + v.y + v.z + v.w;
  float q = v.x * v.x + v.y * v.y + v.z * v.z + v.w * v.w;
#pragma unroll
  for (int m = 32; m >= 1; m >>= 1) { s += __shfl_xor(s, m); q += __shfl_xor(q, m); }
  __shared__ float rs[4], rq[4];
  if ((tid & 63) == 0) { rs[tid >> 6] = s; rq[tid >> 6] = q; }
  __syncthreads();
  s = rs[0] + rs[1] + rs[2] + rs[3];
  q = rq[0] + rq[1] + rq[2] + rq[3];
  const float mu = s * (1.f / 1024.f);
  const float inv = rsqrtf(q * (1.f / 1024.f) - mu * mu + 1e-5f);
  const float4 g4 = *(const float4*)(gw + tid * 4);
  const float4 b4 = *(const float4*)(bw + tid * 4);
  float4 o;
  o.x = (v.x - mu) * inv * g4.x + b4.x;
  o.y = (v.y - mu) * inv * g4.y + b4.y;
  o.z = (v.z - mu) * inv * g4.z + b4.z;
  o.w = (v.w - mu) * inv * g4.w + b4.w;
  if (outf) *(float4*)(outf + off) = o;
  if (outb) {
    u16x4 ob = {f2b(o.x), f2b(o.y), f2b(o.z), f2b(o.w)};
    *(u16x4*)(outb + off) = ob;
  }
}

// ---------- launch ----------
extern "C" void kernel_launch(void* const* d_in, const int* in_sizes, int n_in,
                              void* d_out, int out_size, void* d_ws, size_t ws_size,
                              hipStream_t stream) {
  (void)in_sizes; (void)n_in; (void)out_size; (void)ws_size;
  const float* src   = (const float*)d_in[0];
  const float* abias = (const float*)d_in[1];
  const float* Wqkv  = (const float*)d_in[2];
  const float* bqkv  = (const float*)d_in[3];
  const float* Wo    = (const float*)d_in[4];
  const float* bo    = (const float*)d_in[5];
  const float* g1    = (const float*)d_in[6];
  const float* b1n   = (const float*)d_in[7];
  const float* g2    = (const float*)d_in[8];
  const float* b2n   = (const float*)d_in[9];
  const float* W1    = (const float*)d_in[10];
  const float* b1    = (const float*)d_in[11];
  const float* W2    = (const float*)d_in[12];
  const float* b2    = (const float*)d_in[13];
  float* out = (float*)d_out;

  char* ws = (char*)d_ws;
  const size_t MB = 1024 * 1024;
  // lifetime-aliased layout, <=104 MB
  u16* srcb  = (u16*)(ws + 0 * MB);      // dead after QKV gemm
  u16* ctxb  = (u16*)(ws + 0 * MB);      // alias (attn out, dead after Wo)
  u16* xb    = (u16*)(ws + 0 * MB);      // alias (ln1 out; resid for final LN)
  u16* Wqkvb = (u16*)(ws + 8 * MB);      // dead after QKV gemm
  u16* Wob   = (u16*)(ws + 14 * MB);     // dead after Wo gemm
  u16* W2b   = (u16*)(ws + 24 * MB);     // live until FF2
  u16* qkvb  = (u16*)(ws + 32 * MB);     // Q,K (V goes to Vt); dead after attn
  u16* Vt    = (u16*)(ws + 56 * MB);     // 8 MB; dead after attn
  u16* hb    = (u16*)(ws + 32 * MB);     // alias (FF1 out, 32 MB)
  u16* parts = (u16*)(ws + 64 * MB);     // 32 MB: bf16 split-K x4 partials
  u16* W1b   = (u16*)(ws + 96 * MB);     // 8 MB; dead after FF1

  // one fused cast launch (src, Wqkv, Wo, W1, W2), 8 floats/thread
  CastArgs ca;
  ca.in[0] = src;  ca.out[0] = srcb;
  ca.in[1] = Wqkv; ca.out[1] = Wqkvb;
  ca.in[2] = Wo;   ca.out[2] = Wob;
  ca.in[3] = W1;   ca.out[3] = W1b;
  ca.in[4] = W2;   ca.out[4] = W2b;
  ca.cum[0] = 0;
  ca.cum[1] = 524288;
  ca.cum[2] = 524288 + 393216;
  ca.cum[3] = 524288 + 393216 + 131072;
  ca.cum[4] = 524288 + 393216 + 131072 + 524288;
  ca.cum[5] = 2097152;
  cast_multi<<<2097152 / 256, 256, 0, stream>>>(ca);

  // qkv = src @ Wqkv^T + bqkv -> Q,K into qkvb; V written transposed to Vt
  gemm_nt<false, true><<<dim3(3072 / 128, 4096 / 128), 256, 0, stream>>>(
      srcb, Wqkvb, bqkv, qkvb, Vt, 4096, 3072, 1024);
  // attention -> ctx bf16 [4096, 1024]
  attn_kernel<<<2048, 256, 0, stream>>>(qkvb, Vt, abias, ctxb);
  // Wo split-K x4 (bf16 partials, 1024 blocks = 4/CU)
  gemm_nt_splitk<<<dim3(1024 / 128, 4096 / 128, 4), 256, 0, stream>>>(
      ctxb, Wob, parts, 4096, 1024, 1024, 256);
  // x = LN(sum parts + bo + src) -> bf16 only
  ln_sum_kernel<4, false><<<4096, 256, 0, stream>>>(
      parts, src, bo, g1, b1n, nullptr, xb);
  // h = gelu(x @ W1^T + b1) -> bf16 [4096, 4096]
  gemm_nt<true, false><<<dim3(4096 / 128, 4096 / 128), 256, 0, stream>>>(
      xb, W1b, b1, hb, nullptr, 4096, 4096, 1024);
  // FF2 split-K x4 (bf16 partials)
  gemm_nt_splitk<<<dim3(1024 / 128, 4096 / 128, 4), 256, 0, stream>>>(
      hb, W2b, parts, 4096, 1024, 4096, 1024);
  // out = LN(sum parts + b2 + x)   (x as bf16 residual)
  ln_sum_kernel<4, true><<<4096, 256, 0, stream>>>(
      parts, xb, b2, g2, b2n, out, nullptr);
}

// Round 21
// 271.696 us; speedup vs baseline: 1.1921x; 1.0581x over previous
//
#include <hip/hip_runtime.h>
#include <cstdint>

typedef unsigned short u16;
typedef __bf16 bf16x8 __attribute__((ext_vector_type(8)));
typedef float f32x4 __attribute__((ext_vector_type(4)));
typedef unsigned short u16x8 __attribute__((ext_vector_type(8)));
typedef unsigned short u16x4 __attribute__((ext_vector_type(4)));

// ---------- helpers ----------
__device__ __forceinline__ u16 f2b(float f) {  // fp32 -> bf16 RNE
  union { float f; unsigned u; } x; x.f = f;
  unsigned r = (x.u + 0x7FFFu + ((x.u >> 16) & 1u)) >> 16;
  return (u16)r;
}
__device__ __forceinline__ float b2f(u16 v) {
  union { unsigned u; float f; } x; x.u = (unsigned)v << 16; return x.f;
}

__device__ __forceinline__ void gload_lds16(const void* g, void* l) {
  __builtin_amdgcn_global_load_lds(
      (__attribute__((address_space(1))) void*)(uintptr_t)g,
      (__attribute__((address_space(3))) void*)(uintptr_t)l, 16, 0, 0);
}

// ---------- fused fp32 -> bf16 cast over 5 regions (8 floats/thread) ----------
struct CastArgs {
  const float* in[5];
  u16* out[5];
  int cum[6];   // cumulative float8 counts
};
__global__ void cast_multi(CastArgs a) {
  const int i = blockIdx.x * 256 + threadIdx.x;
  int r = 0;
#pragma unroll
  for (int k = 1; k < 5; ++k) r += (i >= a.cum[k]);
  const int local = i - a.cum[r];
  const float4 v0 = *(const float4*)(a.in[r] + (size_t)local * 8);
  const float4 v1 = *(const float4*)(a.in[r] + (size_t)local * 8 + 4);
  u16x8 o = {f2b(v0.x), f2b(v0.y), f2b(v0.z), f2b(v0.w),
             f2b(v1.x), f2b(v1.y), f2b(v1.z), f2b(v1.w)};
  *(u16x8*)(a.out[r] + (size_t)local * 8) = o;
}

// ---------- GEMM 128x128 (2-barrier), T2 chunk-swizzled LDS ----------
// WRITE_VT: for QKV gemm, cols >= 2048 (V part) go transposed into Vt.
template<bool GELU_ACT, bool WRITE_VT>
__global__ void gemm_nt(const u16* __restrict__ A, const u16* __restrict__ Bw,
                        const float* __restrict__ bias, u16* __restrict__ Cb,
                        u16* __restrict__ Vt, int M, int N, int K) {
  __shared__ u16 As[2][128 * 32];
  __shared__ u16 Bs[2][128 * 32];
  const int tid = threadIdx.x;
  const int lane = tid & 63, wid = tid >> 6;
  const int bm = blockIdx.y * 128, bn = blockIdx.x * 128;
  const int wm = wid >> 1, wn = wid & 1;
  const int r = lane & 15, g = lane >> 4;
  const int s4 = (r >> 1) & 3;           // per-lane read swizzle

  auto stage = [&](int buf, int k0) {
#pragma unroll
    for (int i = 0; i < 2; ++i) {
      const int c = tid + i * 256;
      const int row = c >> 2, ch = c & 3;
      const int gs = ch ^ ((row >> 1) & 3);
      gload_lds16(A + (size_t)(bm + row) * K + k0 + gs * 8, &As[buf][c * 8]);
      gload_lds16(Bw + (size_t)(bn + row) * K + k0 + gs * 8, &Bs[buf][c * 8]);
    }
  };

  f32x4 acc[4][4] = {};
  stage(0, 0);
  __syncthreads();
  const int nk = K >> 5;
  int cur = 0;
  for (int kt = 0; kt < nk; ++kt) {
    if (kt + 1 < nk) stage(cur ^ 1, (kt + 1) * 32);
    bf16x8 af[4], bfr[4];
#pragma unroll
    for (int m = 0; m < 4; ++m)
      af[m] = *(const bf16x8*)&As[cur][(wm * 64 + m * 16 + r) * 32 + (g ^ s4) * 8];
#pragma unroll
    for (int n = 0; n < 4; ++n)
      bfr[n] = *(const bf16x8*)&Bs[cur][(wn * 64 + n * 16 + r) * 32 + (g ^ s4) * 8];
#pragma unroll
    for (int m = 0; m < 4; ++m)
#pragma unroll
      for (int n = 0; n < 4; ++n)
        acc[m][n] = __builtin_amdgcn_mfma_f32_16x16x32_bf16(af[m], bfr[n], acc[m][n], 0, 0, 0);
    __syncthreads();
    cur ^= 1;
  }
#pragma unroll
  for (int m = 0; m < 4; ++m) {
    const int row0 = bm + wm * 64 + m * 16 + g * 4;
#pragma unroll
    for (int n = 0; n < 4; ++n) {
      const int col = bn + wn * 64 + n * 16 + r;
      const float bv = bias[col];
      if (WRITE_VT && col >= 2048) {
        // V part: write transposed. batch = row0>>10, s0 = row0&1023.
        const int hv = col - 2048;
        const int bb = row0 >> 10, s0 = row0 & 1023;
        u16x4 ov;
#pragma unroll
        for (int j = 0; j < 4; ++j) ov[j] = f2b(acc[m][n][j] + bv);
        *(u16x4*)(Vt + (((size_t)(bb * 16 + (hv >> 6))) * 64 + (hv & 63)) * 1024 + s0) = ov;
      } else {
#pragma unroll
        for (int j = 0; j < 4; ++j) {
          float v = acc[m][n][j] + bv;
          if (GELU_ACT) v = 0.5f * v * (1.f + erff(v * 0.70710678118654752f));
          Cb[(size_t)(row0 + j) * N + col] = f2b(v);
        }
      }
    }
  }
}

// ---------- GEMM 128x128 split-K (chunk-swizzled): bf16 partials ----------
__global__ void gemm_nt_splitk(const u16* __restrict__ A, const u16* __restrict__ Bw,
                               u16* __restrict__ parts, int M, int N, int K, int Kc) {
  __shared__ u16 As[2][128 * 32];
  __shared__ u16 Bs[2][128 * 32];
  const int tid = threadIdx.x;
  const int lane = tid & 63, wid = tid >> 6;
  const int bm = blockIdx.y * 128, bn = blockIdx.x * 128;
  const int kbase = blockIdx.z * Kc;
  const int wm = wid >> 1, wn = wid & 1;
  const int r = lane & 15, g = lane >> 4;
  const int s4 = (r >> 1) & 3;

  auto stage = [&](int buf, int k0) {
#pragma unroll
    for (int i = 0; i < 2; ++i) {
      const int c = tid + i * 256;
      const int row = c >> 2, ch = c & 3;
      const int gs = ch ^ ((row >> 1) & 3);
      gload_lds16(A + (size_t)(bm + row) * K + k0 + gs * 8, &As[buf][c * 8]);
      gload_lds16(Bw + (size_t)(bn + row) * K + k0 + gs * 8, &Bs[buf][c * 8]);
    }
  };

  f32x4 acc[4][4] = {};
  stage(0, kbase);
  __syncthreads();
  const int nk = Kc >> 5;
  int cur = 0;
  for (int kt = 0; kt < nk; ++kt) {
    if (kt + 1 < nk) stage(cur ^ 1, kbase + (kt + 1) * 32);
    bf16x8 af[4], bfr[4];
#pragma unroll
    for (int m = 0; m < 4; ++m)
      af[m] = *(const bf16x8*)&As[cur][(wm * 64 + m * 16 + r) * 32 + (g ^ s4) * 8];
#pragma unroll
    for (int n = 0; n < 4; ++n)
      bfr[n] = *(const bf16x8*)&Bs[cur][(wn * 64 + n * 16 + r) * 32 + (g ^ s4) * 8];
#pragma unroll
    for (int m = 0; m < 4; ++m)
#pragma unroll
      for (int n = 0; n < 4; ++n)
        acc[m][n] = __builtin_amdgcn_mfma_f32_16x16x32_bf16(af[m], bfr[n], acc[m][n], 0, 0, 0);
    __syncthreads();
    cur ^= 1;
  }
  u16* Cp = parts + (size_t)blockIdx.z * M * N;
#pragma unroll
  for (int m = 0; m < 4; ++m) {
    const int row0 = bm + wm * 64 + m * 16 + g * 4;
#pragma unroll
    for (int n = 0; n < 4; ++n) {
      const int col = bn + wn * 64 + n * 16 + r;
#pragma unroll
      for (int j = 0; j < 4; ++j)
        Cp[(size_t)(row0 + j) * N + col] = f2b(acc[m][n][j]);
    }
  }
}

// ---------- fused attention v16 (r18 best: QBLK=32, 2-deep prefetch, XCD bias) ----
__global__ __launch_bounds__(256) void attn_kernel(
    const u16* __restrict__ qkv, const u16* __restrict__ Vt,
    const float* __restrict__ bias, u16* __restrict__ ctx) {
  const int fid = blockIdx.x;
  const int xcd = fid & 7, slot = fid >> 3;
  const int G = xcd * 64 + (slot >> 2);
  const int b = slot & 3;
  const int h = G >> 5;
  const int q0 = (G & 31) * 32;
  const int tid = threadIdx.x;
  const int lane = tid & 63, wid = tid >> 6;
  const int r = lane & 15, g = lane >> 4;
  const int bh = b * 16 + h;

  __shared__ __align__(16) u16 PB[2][16 * 1024];

  const size_t qb0 = (size_t)(b * 1024 + q0 + r) * 3072 + h * 64;
  const size_t qb1 = (size_t)(b * 1024 + q0 + 16 + r) * 3072 + h * 64;
  const bf16x8 aq00 = *(const bf16x8*)(qkv + qb0 + g * 8);
  const bf16x8 aq01 = *(const bf16x8*)(qkv + qb0 + 32 + g * 8);
  const bf16x8 aq10 = *(const bf16x8*)(qkv + qb1 + g * 8);
  const bf16x8 aq11 = *(const bf16x8*)(qkv + qb1 + 32 + g * 8);

  const int n0 = wid * 256;

  const u16* kptr = qkv + (size_t)(b * 1024 + n0 + r) * 3072 + 1024 + h * 64;
  const size_t kstep = (size_t)16 * 3072;
  bf16x8 k0a = *(const bf16x8*)(kptr + g * 8);
  bf16x8 k1a = *(const bf16x8*)(kptr + 32 + g * 8);
#pragma unroll
  for (int nt = 0; nt < 16; ++nt) {
    bf16x8 k0b, k1b;
    if (nt + 1 < 16) {
      const u16* kn = kptr + (size_t)(nt + 1) * kstep;
      k0b = *(const bf16x8*)(kn + g * 8);
      k1b = *(const bf16x8*)(kn + 32 + g * 8);
    }
    f32x4 a0 = {0.f, 0.f, 0.f, 0.f}, a1 = {0.f, 0.f, 0.f, 0.f};
    a0 = __builtin_amdgcn_mfma_f32_16x16x32_bf16(k0a, aq00, a0, 0, 0, 0);
    a1 = __builtin_amdgcn_mfma_f32_16x16x32_bf16(k0a, aq10, a1, 0, 0, 0);
    a0 = __builtin_amdgcn_mfma_f32_16x16x32_bf16(k1a, aq01, a0, 0, 0, 0);
    a1 = __builtin_amdgcn_mfma_f32_16x16x32_bf16(k1a, aq11, a1, 0, 0, 0);
    const int col = n0 + nt * 16 + g * 4;
    const int idx = r * 1024 + (col ^ ((r & 15) << 3));
    u16x4 o0 = {f2b(a0[0] * 0.125f), f2b(a0[1] * 0.125f),
                f2b(a0[2] * 0.125f), f2b(a0[3] * 0.125f)};
    u16x4 o1 = {f2b(a1[0] * 0.125f), f2b(a1[1] * 0.125f),
                f2b(a1[2] * 0.125f), f2b(a1[3] * 0.125f)};
    *(u16x4*)&PB[0][idx] = o0;
    *(u16x4*)&PB[1][idx] = o1;
    k0a = k0b;
    k1a = k1b;
  }
  __syncthreads();

#pragma unroll
  for (int tr = 0; tr < 8; ++tr) {
    const int t = tr & 1, rr = tr >> 1;
    const int row = wid * 4 + rr;
    const int swz = (row & 15) << 3;
    u16* prow = &PB[t][row * 1024];
    const float* brow = bias + ((size_t)h * 1024 + q0 + t * 16 + row) * 1024;
    const int c0 = lane * 16;
    float bb[16];
    *(float4*)&bb[0]  = *(const float4*)(brow + c0);
    *(float4*)&bb[4]  = *(const float4*)(brow + c0 + 4);
    *(float4*)&bb[8]  = *(const float4*)(brow + c0 + 8);
    *(float4*)&bb[12] = *(const float4*)(brow + c0 + 12);
    const u16x8 v0 = *(const u16x8*)&prow[c0 ^ swz];
    const u16x8 v1 = *(const u16x8*)&prow[(c0 + 8) ^ swz];
    float f[16];
#pragma unroll
    for (int k = 0; k < 8; ++k) {
      f[k]     = b2f(v0[k]) + bb[k];
      f[8 + k] = b2f(v1[k]) + bb[8 + k];
    }
    float m = f[0];
#pragma unroll
    for (int k = 1; k < 16; ++k) m = fmaxf(m, f[k]);
    m = fmaxf(m, __shfl_xor(m, 1));  m = fmaxf(m, __shfl_xor(m, 2));
    m = fmaxf(m, __shfl_xor(m, 4));  m = fmaxf(m, __shfl_xor(m, 8));
    m = fmaxf(m, __shfl_xor(m, 16)); m = fmaxf(m, __shfl_xor(m, 32));
    float s = 0.f;
#pragma unroll
    for (int k = 0; k < 16; ++k) { f[k] = __expf(f[k] - m); s += f[k]; }
    s += __shfl_xor(s, 1);  s += __shfl_xor(s, 2);
    s += __shfl_xor(s, 4);  s += __shfl_xor(s, 8);
    s += __shfl_xor(s, 16); s += __shfl_xor(s, 32);
    const float inv = 1.f / s;
    u16x8 o0, o1;
#pragma unroll
    for (int k = 0; k < 8; ++k) {
      o0[k] = f2b(f[k] * inv);
      o1[k] = f2b(f[8 + k] * inv);
    }
    *(u16x8*)&prow[c0 ^ swz] = o0;
    *(u16x8*)&prow[(c0 + 8) ^ swz] = o1;
  }
  __syncthreads();

  f32x4 oa = {0.f, 0.f, 0.f, 0.f}, ob = {0.f, 0.f, 0.f, 0.f};
  const u16* vrow = Vt + ((size_t)bh * 64 + wid * 16 + r) * 1024;
  bf16x8 vba = *(const bf16x8*)(vrow + g * 8);
#pragma unroll
  for (int ks = 0; ks < 32; ++ks) {
    bf16x8 vbb;
    if (ks + 1 < 32) vbb = *(const bf16x8*)(vrow + (ks + 1) * 32 + g * 8);
    const int off = (ks * 32 + g * 8) ^ ((r & 15) << 3);
    const bf16x8 pa0 = *(const bf16x8*)&PB[0][r * 1024 + off];
    const bf16x8 pa1 = *(const bf16x8*)&PB[1][r * 1024 + off];
    oa = __builtin_amdgcn_mfma_f32_16x16x32_bf16(pa0, vba, oa, 0, 0, 0);
    ob = __builtin_amdgcn_mfma_f32_16x16x32_bf16(pa1, vba, ob, 0, 0, 0);
    vba = vbb;
  }
#pragma unroll
  for (int j = 0; j < 4; ++j) {
    ctx[(size_t)(b * 1024 + q0 + g * 4 + j) * 1024 + h * 64 + wid * 16 + r] = f2b(oa[j]);
    ctx[(size_t)(b * 1024 + q0 + 16 + g * 4 + j) * 1024 + h * 64 + wid * 16 + r] = f2b(ob[j]);
  }
}

// ---------- LayerNorm over D=1024 with NP bf16 split-K partials + resid + colbias --
template<int NP, bool RESID_BF16>
__global__ void ln_sum_kernel(const u16* __restrict__ parts,
                              const void* __restrict__ resid,
                              const float* __restrict__ cbias,
                              const float* __restrict__ gw, const float* __restrict__ bw,
                              float* __restrict__ outf, u16* __restrict__ outb) {
  const int row = blockIdx.x, tid = threadIdx.x;
  const size_t off = (size_t)row * 1024 + tid * 4;
  float4 v;
  if (RESID_BF16) {
    const u16x4 rb = *(const u16x4*)((const u16*)resid + off);
    v.x = b2f(rb[0]); v.y = b2f(rb[1]); v.z = b2f(rb[2]); v.w = b2f(rb[3]);
  } else {
    v = *(const float4*)((const float*)resid + off);
  }
  const float4 cb = *(const float4*)(cbias + tid * 4);
  v.x += cb.x; v.y += cb.y; v.z += cb.z; v.w += cb.w;
#pragma unroll
  for (int p = 0; p < NP; ++p) {
    const u16x4 a = *(const u16x4*)(parts + (size_t)p * 4096 * 1024 + off);
    v.x += b2f(a[0]); v.y += b2f(a[1]); v.z += b2f(a[2]); v.w += b2f(a[3]);
  }
  float s = v.x + v.y + v.z + v.w;
  float q = v.x * v.x + v.y * v.y + v.z * v.z + v.w * v.w;
#pragma unroll
  for (int m = 32; m >= 1; m >>= 1) { s += __shfl_xor(s, m); q += __shfl_xor(q, m); }
  __shared__ float rs[4], rq[4];
  if ((tid & 63) == 0) { rs[tid >> 6] = s; rq[tid >> 6] = q; }
  __syncthreads();
  s = rs[0] + rs[1] + rs[2] + rs[3];
  q = rq[0] + rq[1] + rq[2] + rq[3];
  const float mu = s * (1.f / 1024.f);
  const float inv = rsqrtf(q * (1.f / 1024.f) - mu * mu + 1e-5f);
  const float4 g4 = *(const float4*)(gw + tid * 4);
  const float4 b4 = *(const float4*)(bw + tid * 4);
  float4 o;
  o.x = (v.x - mu) * inv * g4.x + b4.x;
  o.y = (v.y - mu) * inv * g4.y + b4.y;
  o.z = (v.z - mu) * inv * g4.z + b4.z;
  o.w = (v.w - mu) * inv * g4.w + b4.w;
  if (outf) *(float4*)(outf + off) = o;
  if (outb) {
    u16x4 ob = {f2b(o.x), f2b(o.y), f2b(o.z), f2b(o.w)};
    *(u16x4*)(outb + off) = ob;
  }
}

// ---------- launch ----------
extern "C" void kernel_launch(void* const* d_in, const int* in_sizes, int n_in,
                              void* d_out, int out_size, void* d_ws, size_t ws_size,
                              hipStream_t stream) {
  (void)in_sizes; (void)n_in; (void)out_size; (void)ws_size;
  const float* src   = (const float*)d_in[0];
  const float* abias = (const float*)d_in[1];
  const float* Wqkv  = (const float*)d_in[2];
  const float* bqkv  = (const float*)d_in[3];
  const float* Wo    = (const float*)d_in[4];
  const float* bo    = (const float*)d_in[5];
  const float* g1    = (const float*)d_in[6];
  const float* b1n   = (const float*)d_in[7];
  const float* g2    = (const float*)d_in[8];
  const float* b2n   = (const float*)d_in[9];
  const float* W1    = (const float*)d_in[10];
  const float* b1    = (const float*)d_in[11];
  const float* W2    = (const float*)d_in[12];
  const float* b2    = (const float*)d_in[13];
  float* out = (float*)d_out;

  char* ws = (char*)d_ws;
  const size_t MB = 1024 * 1024;
  // lifetime-aliased layout, <=104 MB
  u16* srcb  = (u16*)(ws + 0 * MB);      // dead after QKV gemm
  u16* ctxb  = (u16*)(ws + 0 * MB);      // alias (attn out, dead after Wo)
  u16* xb    = (u16*)(ws + 0 * MB);      // alias (ln1 out; resid for final LN)
  u16* Wqkvb = (u16*)(ws + 8 * MB);      // dead after QKV gemm
  u16* Wob   = (u16*)(ws + 14 * MB);     // dead after Wo gemm
  u16* W2b   = (u16*)(ws + 24 * MB);     // live until FF2
  u16* qkvb  = (u16*)(ws + 32 * MB);     // Q,K (V goes to Vt); dead after attn
  u16* Vt    = (u16*)(ws + 56 * MB);     // 8 MB; dead after attn
  u16* hb    = (u16*)(ws + 32 * MB);     // alias (FF1 out, 32 MB)
  u16* parts = (u16*)(ws + 64 * MB);     // 16 MB: bf16 split-K x2 partials
  u16* W1b   = (u16*)(ws + 96 * MB);     // 8 MB; dead after FF1

  // one fused cast launch (src, Wqkv, Wo, W1, W2), 8 floats/thread
  CastArgs ca;
  ca.in[0] = src;  ca.out[0] = srcb;
  ca.in[1] = Wqkv; ca.out[1] = Wqkvb;
  ca.in[2] = Wo;   ca.out[2] = Wob;
  ca.in[3] = W1;   ca.out[3] = W1b;
  ca.in[4] = W2;   ca.out[4] = W2b;
  ca.cum[0] = 0;
  ca.cum[1] = 524288;                        // src  4096*1024/8
  ca.cum[2] = 524288 + 393216;               // Wqkv 3072*1024/8
  ca.cum[3] = 524288 + 393216 + 131072;      // Wo   1024*1024/8
  ca.cum[4] = 524288 + 393216 + 131072 + 524288;  // W1
  ca.cum[5] = 2097152;                       // + W2
  cast_multi<<<2097152 / 256, 256, 0, stream>>>(ca);

  // qkv = src @ Wqkv^T + bqkv -> Q,K into qkvb; V written transposed to Vt
  gemm_nt<false, true><<<dim3(3072 / 128, 4096 / 128), 256, 0, stream>>>(
      srcb, Wqkvb, bqkv, qkvb, Vt, 4096, 3072, 1024);
  // attention -> ctx bf16 [4096, 1024]
  attn_kernel<<<2048, 256, 0, stream>>>(qkvb, Vt, abias, ctxb);
  // Wo split-K x2 (bf16 partials)
  gemm_nt_splitk<<<dim3(1024 / 128, 4096 / 128, 2), 256, 0, stream>>>(
      ctxb, Wob, parts, 4096, 1024, 1024, 512);
  // x = LN(part0+part1+bo+src) -> bf16 only
  ln_sum_kernel<2, false><<<4096, 256, 0, stream>>>(
      parts, src, bo, g1, b1n, nullptr, xb);
  // h = gelu(x @ W1^T + b1) -> bf16 [4096, 4096]
  gemm_nt<true, false><<<dim3(4096 / 128, 4096 / 128), 256, 0, stream>>>(
      xb, W1b, b1, hb, nullptr, 4096, 4096, 1024);
  // FF2 split-K x2 (bf16 partials)
  gemm_nt_splitk<<<dim3(1024 / 128, 4096 / 128, 2), 256, 0, stream>>>(
      hb, W2b, parts, 4096, 1024, 4096, 2048);
  // out = LN(part0+part1+b2+x)   (x as bf16 residual)
  ln_sum_kernel<2, true><<<4096, 256, 0, stream>>>(
      parts, xb, b2, g2, b2n, out, nullptr);
}